// Round 4
// baseline (230.224 us; speedup 1.0000x reference)
//
#include <hip/hip_runtime.h>

#define N_NODES 100000
#define IN_F    256
#define OUT_F   256
#define BATCH   50000
#define NSAMP   25
#define K2      512

typedef _Float16 f16_t;
typedef f16_t f16x8 __attribute__((ext_vector_type(8)));
typedef float f32x4 __attribute__((ext_vector_type(4)));
typedef __bf16 bf16_t;
typedef bf16_t bf16x8 __attribute__((ext_vector_type(8)));

// workspace layout (bytes)
#define PNEIGH_OFF 51200000L                 // 100000*256*2
#define WG_OFF     102400000L
#define WS_NEED    (WG_OFF + 512L * 256 * 2)

__device__ __forceinline__ float h2f(unsigned short u) {
    union { unsigned short u; f16_t h; } t; t.u = u; return (float)t.h;
}

// ---------------- Kernel 0: rearrange W -> Wg[512][256] f16 ----------------
__global__ void wconv(const float* __restrict__ W, f16_t* __restrict__ Wg) {
    int idx = blockIdx.x * 256 + threadIdx.x;
    int j = idx >> 8, k = idx & 255;
    float v = (j < 256) ? W[j * K2 + k] : W[(j - 256) * K2 + 256 + k];
    Wg[idx] = (f16_t)v;
}

// ---------------- Kernel 1: P = F @ Wg^T ----------------
// Block: 64 feature rows x 512 P-cols (two 256-col groups done sequentially).
// Wave tile per group: 64 cols x 64 rows (acc 64 VGPR). Wg fragments are
// register-prefetched one k-step ahead to break the L2-load -> MFMA chain.
__global__ __launch_bounds__(256, 3) void proj_gemm(
    const float* __restrict__ features, const f16_t* __restrict__ Wg,
    f16_t* __restrict__ Pself, f16_t* __restrict__ Pneigh)
{
    __shared__ unsigned short atile[64 * 256];  // f16 bits, XOR-swizzled, 32 KB
    const int tid = threadIdx.x, lane = tid & 63, w = tid >> 6;
    const long gr0 = (long)blockIdx.x * 64;

    #pragma unroll
    for (int i = 0; i < 16; ++i) {
        int q = tid + i * 256;
        int row = q >> 6, c4 = (q & 63) * 4;
        long srow = gr0 + row; if (srow > N_NODES - 1) srow = N_NODES - 1;
        float4 f = *(const float4*)&features[srow * IN_F + c4];
        union { ushort4 u; f16_t h[4]; } t;
        t.h[0] = (f16_t)f.x; t.h[1] = (f16_t)f.y;
        t.h[2] = (f16_t)f.z; t.h[3] = (f16_t)f.w;
        *(ushort4*)&atile[(row * 256 + c4) ^ ((row & 7) << 3)] = t.u;
    }
    __syncthreads();

    const int q16 = lane >> 4, r16 = lane & 15;

    #pragma unroll
    for (int cg = 0; cg < 2; ++cg) {
        const int c0 = cg * 256 + w * 64;     // global P-col base of this wave

        f32x4 acc[4][4];
        #pragma unroll
        for (int ct = 0; ct < 4; ++ct)
            #pragma unroll
            for (int rt = 0; rt < 4; ++rt) acc[ct][rt] = (f32x4){0.f, 0.f, 0.f, 0.f};

        f16x8 wg[2][4];
        #pragma unroll
        for (int ct = 0; ct < 4; ++ct)
            wg[0][ct] = *(const f16x8*)&Wg[(long)(c0 + ct * 16 + r16) * 256 + q16 * 8];

        #pragma unroll
        for (int s = 0; s < 8; ++s) {
            const int kb = s * 32 + q16 * 8;
            // prefetch next k-step's Wg fragments (issues before MFMAs below)
            if (s < 7) {
                const int kbn = kb + 32;
                #pragma unroll
                for (int ct = 0; ct < 4; ++ct)
                    wg[(s + 1) & 1][ct] =
                        *(const f16x8*)&Wg[(long)(c0 + ct * 16 + r16) * 256 + kbn];
            }
            f16x8 bfr[4];
            #pragma unroll
            for (int rt = 0; rt < 4; ++rt) {
                int row = rt * 16 + r16;
                bfr[rt] = *(const f16x8*)&atile[(row * 256 + kb) ^ ((row & 7) << 3)];
            }
            #pragma unroll
            for (int ct = 0; ct < 4; ++ct)
                #pragma unroll
                for (int rt = 0; rt < 4; ++rt)
                    acc[ct][rt] = __builtin_amdgcn_mfma_f32_16x16x32_f16(
                        wg[s & 1][ct], bfr[rt], acc[ct][rt], 0, 0, 0);
        }

        f16_t* __restrict__ Pdst = (cg == 0) ? Pself : Pneigh;
        const int colb_base = w * 64 + q16 * 4;     // col within the 256-col group
        #pragma unroll
        for (int ct = 0; ct < 4; ++ct) {
            const int colb = colb_base + ct * 16;
            #pragma unroll
            for (int rt = 0; rt < 4; ++rt) {
                const long row = gr0 + rt * 16 + r16;
                if (row < N_NODES) {
                    union { ushort4 u; f16_t h[4]; } t;
                    t.h[0] = (f16_t)acc[ct][rt][0]; t.h[1] = (f16_t)acc[ct][rt][1];
                    t.h[2] = (f16_t)acc[ct][rt][2]; t.h[3] = (f16_t)acc[ct][rt][3];
                    *(ushort4*)&Pdst[row * 256 + colb] = t.u;
                }
            }
        }
    }
}

// ---------------- Kernel 2: gather + mean-add, 2 rows per wave ----------------
__global__ __launch_bounds__(256) void gather_add(
    const f16_t* __restrict__ Pself, const f16_t* __restrict__ Pneigh,
    const int* __restrict__ node_idx, const int* __restrict__ neigh_idx,
    float* __restrict__ out)
{
    const int tid = threadIdx.x, lane = tid & 63, w = tid >> 6;
    const long b0 = (long)blockIdx.x * 8 + w * 2;   // rows b0, b0+1
    const int c4 = lane * 4;

    int ns0[NSAMP], ns1[NSAMP];
    #pragma unroll
    for (int s = 0; s < NSAMP; ++s) ns0[s] = neigh_idx[b0 * NSAMP + s];
    #pragma unroll
    for (int s = 0; s < NSAMP; ++s) ns1[s] = neigh_idx[(b0 + 1) * NSAMP + s];
    const int sn0 = node_idx[b0], sn1 = node_idx[b0 + 1];

    const ushort4 sv0 = *(const ushort4*)&Pself[(long)sn0 * 256 + c4];
    const ushort4 sv1 = *(const ushort4*)&Pself[(long)sn1 * 256 + c4];

    ushort4 v0[13], v1[13];
    #pragma unroll
    for (int s = 0; s < 13; ++s) v0[s] = *(const ushort4*)&Pneigh[(long)ns0[s] * 256 + c4];
    #pragma unroll
    for (int s = 0; s < 13; ++s) v1[s] = *(const ushort4*)&Pneigh[(long)ns1[s] * 256 + c4];

    float4 a0 = make_float4(0.f, 0.f, 0.f, 0.f);
    float4 a1 = make_float4(0.f, 0.f, 0.f, 0.f);
    #pragma unroll
    for (int s = 0; s < 13; ++s) {
        a0.x += h2f(v0[s].x); a0.y += h2f(v0[s].y);
        a0.z += h2f(v0[s].z); a0.w += h2f(v0[s].w);
    }
    #pragma unroll
    for (int s = 13; s < NSAMP; ++s)
        v0[s - 13] = *(const ushort4*)&Pneigh[(long)ns0[s] * 256 + c4];
    #pragma unroll
    for (int s = 0; s < 13; ++s) {
        a1.x += h2f(v1[s].x); a1.y += h2f(v1[s].y);
        a1.z += h2f(v1[s].z); a1.w += h2f(v1[s].w);
    }
    #pragma unroll
    for (int s = 13; s < NSAMP; ++s)
        v1[s - 13] = *(const ushort4*)&Pneigh[(long)ns1[s] * 256 + c4];
    #pragma unroll
    for (int s = 0; s < 12; ++s) {
        a0.x += h2f(v0[s].x); a0.y += h2f(v0[s].y);
        a0.z += h2f(v0[s].z); a0.w += h2f(v0[s].w);
        a1.x += h2f(v1[s].x); a1.y += h2f(v1[s].y);
        a1.z += h2f(v1[s].z); a1.w += h2f(v1[s].w);
    }

    const float inv = 1.0f / (float)NSAMP;
    float4 o0, o1;
    o0.x = h2f(sv0.x) + a0.x * inv; o0.y = h2f(sv0.y) + a0.y * inv;
    o0.z = h2f(sv0.z) + a0.z * inv; o0.w = h2f(sv0.w) + a0.w * inv;
    o1.x = h2f(sv1.x) + a1.x * inv; o1.y = h2f(sv1.y) + a1.y * inv;
    o1.z = h2f(sv1.z) + a1.z * inv; o1.w = h2f(sv1.w) + a1.w * inv;
    *(float4*)&out[b0 * OUT_F + c4] = o0;
    *(float4*)&out[(b0 + 1) * OUT_F + c4] = o1;
}

// ---------------- Fallback (monolithic) if ws too small ----------------
__device__ __forceinline__ int swz_bf(int row, int us_idx) {
    return us_idx ^ ((row & 7) << 3);
}
__device__ __forceinline__ void store_bf4(unsigned short* comb, int r, int col, float4 f) {
    union { ushort4 u; bf16_t b[4]; } t;
    t.b[0] = (bf16_t)f.x; t.b[1] = (bf16_t)f.y;
    t.b[2] = (bf16_t)f.z; t.b[3] = (bf16_t)f.w;
    *(ushort4*)&comb[swz_bf(r, r * K2 + col)] = t.u;
}
__global__ __launch_bounds__(256, 4) void sage_fused(
    const float* __restrict__ features, const int* __restrict__ node_idx,
    const int* __restrict__ neigh_idx, const float* __restrict__ W,
    float* __restrict__ out)
{
    __shared__ unsigned short comb[16 * K2];
    const int tid = threadIdx.x, lane = tid & 63, wy = tid >> 6;
    const int b0 = blockIdx.x * 16;
    const int col4 = lane * 4;
    #pragma unroll
    for (int i = 0; i < 4; ++i) {
        const int r = wy * 4 + i;
        const long b = b0 + r;
        int nidx[NSAMP];
        #pragma unroll
        for (int s = 0; s < NSAMP; ++s) nidx[s] = neigh_idx[b * NSAMP + s];
        const int self_n = node_idx[b];
        const float4 sf = *(const float4*)&features[(long)self_n * IN_F + col4];
        float4 v[13];
        #pragma unroll
        for (int s = 0; s < 13; ++s)
            v[s] = *(const float4*)&features[(long)nidx[s] * IN_F + col4];
        float4 acc = v[0];
        #pragma unroll
        for (int s = 1; s < 13; ++s) {
            acc.x += v[s].x; acc.y += v[s].y; acc.z += v[s].z; acc.w += v[s].w;
        }
        #pragma unroll
        for (int s = 13; s < NSAMP; ++s)
            v[s - 13] = *(const float4*)&features[(long)nidx[s] * IN_F + col4];
        #pragma unroll
        for (int s = 0; s < 12; ++s) {
            acc.x += v[s].x; acc.y += v[s].y; acc.z += v[s].z; acc.w += v[s].w;
        }
        const float inv = 1.0f / (float)NSAMP;
        acc.x *= inv; acc.y *= inv; acc.z *= inv; acc.w *= inv;
        store_bf4(comb, r, col4, sf);
        store_bf4(comb, r, IN_F + col4, acc);
    }
    __syncthreads();
    const int c0 = wy * 64, arow = lane & 15, kq = (lane >> 4) * 8;
    f32x4 acc[4];
    #pragma unroll
    for (int t = 0; t < 4; ++t) acc[t] = (f32x4){0.f, 0.f, 0.f, 0.f};
    #pragma unroll
    for (int ks = 0; ks < 16; ++ks) {
        const int kb = ks * 32 + kq;
        const bf16x8 af = *(const bf16x8*)&comb[swz_bf(arow, arow * K2 + kb)];
        #pragma unroll
        for (int t = 0; t < 4; ++t) {
            const float* wp = &W[(long)(c0 + t * 16 + arow) * K2 + kb];
            const float4 w0 = *(const float4*)wp;
            const float4 w1 = *(const float4*)(wp + 4);
            bf16x8 bf;
            bf[0] = (bf16_t)w0.x; bf[1] = (bf16_t)w0.y;
            bf[2] = (bf16_t)w0.z; bf[3] = (bf16_t)w0.w;
            bf[4] = (bf16_t)w1.x; bf[5] = (bf16_t)w1.y;
            bf[6] = (bf16_t)w1.z; bf[7] = (bf16_t)w1.w;
            acc[t] = __builtin_amdgcn_mfma_f32_16x16x32_bf16(af, bf, acc[t], 0, 0, 0);
        }
    }
    #pragma unroll
    for (int t = 0; t < 4; ++t) {
        const int col = c0 + t * 16 + arow;
        #pragma unroll
        for (int j = 0; j < 4; ++j) {
            const int row = b0 + (lane >> 4) * 4 + j;
            out[(long)row * OUT_F + col] = acc[t][j];
        }
    }
}

extern "C" void kernel_launch(void* const* d_in, const int* in_sizes, int n_in,
                              void* d_out, int out_size, void* d_ws, size_t ws_size,
                              hipStream_t stream) {
    const float* features  = (const float*)d_in[0];
    const int*   node_idx  = (const int*)d_in[1];
    const int*   neigh_idx = (const int*)d_in[2];
    const float* W         = (const float*)d_in[3];
    float*       out       = (float*)d_out;

    if (ws_size >= (size_t)WS_NEED) {
        f16_t* Pself  = (f16_t*)d_ws;
        f16_t* Pneigh = (f16_t*)((char*)d_ws + PNEIGH_OFF);
        f16_t* Wg     = (f16_t*)((char*)d_ws + WG_OFF);
        wconv<<<512, 256, 0, stream>>>(W, Wg);
        proj_gemm<<<1563, 256, 0, stream>>>(features, Wg, Pself, Pneigh);
        gather_add<<<BATCH / 8, 256, 0, stream>>>(Pself, Pneigh, node_idx, neigh_idx, out);
    } else {
        sage_fused<<<BATCH / 16, 256, 0, stream>>>(features, node_idx, neigh_idx, W, out);
    }
}

// Round 5
// 154.262 us; speedup vs baseline: 1.4924x; 1.4924x over previous
//
#include <hip/hip_runtime.h>

#define N_NODES 100000
#define IN_F    256
#define OUT_F   256
#define BATCH   50000
#define NSAMP   25
#define K2      512

typedef _Float16 f16_t;
typedef f16_t f16x8 __attribute__((ext_vector_type(8)));
typedef float f32x4 __attribute__((ext_vector_type(4)));
typedef float f32x2 __attribute__((ext_vector_type(2)));
typedef __bf16 bf16_t;
typedef bf16_t bf16x8 __attribute__((ext_vector_type(8)));

#if defined(__has_builtin)
#if __has_builtin(__builtin_amdgcn_cvt_pk_f32_fp8) && __has_builtin(__builtin_amdgcn_cvt_pk_fp8_f32)
#define FP8_HW 1
#endif
#endif
#ifndef FP8_HW
#include <hip/hip_fp8.h>
#endif

// workspace layout (bytes): Pself f16 [100000][256], Pneigh fp8 [100000][256], Wg f16 [512][256]
#define P8_OFF   51200000L
#define WG_OFF   76800000L
#define WS_NEED  (WG_OFF + 512L * 256 * 2)

__device__ __forceinline__ float h2f(unsigned short u) {
    union { unsigned short u; f16_t h; } t; t.u = u; return (float)t.h;
}

// pack 4 f32 -> 4 fp8 e4m3 bytes
__device__ __forceinline__ unsigned int pk_fp8x4(float a, float b, float c, float d) {
#ifdef FP8_HW
    unsigned int r = __builtin_amdgcn_cvt_pk_fp8_f32(a, b, 0u, false);
    r = __builtin_amdgcn_cvt_pk_fp8_f32(c, d, r, true);
    return r;
#else
    union { unsigned char b[4]; unsigned int u; } t;
    t.b[0] = __hip_fp8_e4m3(a).__x; t.b[1] = __hip_fp8_e4m3(b).__x;
    t.b[2] = __hip_fp8_e4m3(c).__x; t.b[3] = __hip_fp8_e4m3(d).__x;
    return t.u;
#endif
}

// decode 4 fp8 bytes -> accumulate into f32x4
__device__ __forceinline__ void acc_fp8x4(unsigned int v, float4& a) {
#ifdef FP8_HW
    f32x2 lo = __builtin_amdgcn_cvt_pk_f32_fp8(v, false);
    f32x2 hi = __builtin_amdgcn_cvt_pk_f32_fp8(v, true);
    a.x += lo[0]; a.y += lo[1]; a.z += hi[0]; a.w += hi[1];
#else
    union { unsigned int u; unsigned char b[4]; } t; t.u = v;
    __hip_fp8_e4m3 e0, e1, e2, e3;
    e0.__x = t.b[0]; e1.__x = t.b[1]; e2.__x = t.b[2]; e3.__x = t.b[3];
    a.x += (float)e0; a.y += (float)e1; a.z += (float)e2; a.w += (float)e3;
#endif
}

// ---------------- Kernel 0: rearrange W -> Wg[512][256] f16 ----------------
__global__ void wconv(const float* __restrict__ W, f16_t* __restrict__ Wg) {
    int idx = blockIdx.x * 256 + threadIdx.x;
    int j = idx >> 8, k = idx & 255;
    float v = (j < 256) ? W[j * K2 + k] : W[(j - 256) * K2 + 256 + k];
    Wg[idx] = (f16_t)v;
}

// ---------------- Kernel 1: P = F @ Wg^T (f16 MFMA, pipelined Wg loads) ----------------
// Block: 64 feature rows x 512 P-cols. Wave w covers cols [w*128, w*128+128):
// waves 0-1 write Pself (f16), waves 2-3 write Pneigh (fp8).
__global__ __launch_bounds__(256, 2) void proj_gemm(
    const float* __restrict__ features, const f16_t* __restrict__ Wg,
    f16_t* __restrict__ Pself, unsigned char* __restrict__ Pneigh8)
{
    __shared__ unsigned short atile[64 * 256];  // f16 bits, XOR-swizzled, 32 KB
    const int tid = threadIdx.x, lane = tid & 63, w = tid >> 6;
    const long gr0 = (long)blockIdx.x * 64;

    #pragma unroll
    for (int i = 0; i < 16; ++i) {
        int q = tid + i * 256;
        int row = q >> 6, c4 = (q & 63) * 4;
        long srow = gr0 + row; if (srow > N_NODES - 1) srow = N_NODES - 1;
        float4 f = *(const float4*)&features[srow * IN_F + c4];
        union { ushort4 u; f16_t h[4]; } t;
        t.h[0] = (f16_t)f.x; t.h[1] = (f16_t)f.y;
        t.h[2] = (f16_t)f.z; t.h[3] = (f16_t)f.w;
        *(ushort4*)&atile[(row * 256 + c4) ^ ((row & 7) << 3)] = t.u;
    }
    __syncthreads();

    const int q16 = lane >> 4, r16 = lane & 15;
    const int c0 = w * 128;
    const f16_t* wbase = Wg + (long)(c0 + r16) * 256 + q16 * 8;

    f32x4 acc[8][4];
    #pragma unroll
    for (int ct = 0; ct < 8; ++ct)
        #pragma unroll
        for (int rt = 0; rt < 4; ++rt) acc[ct][rt] = (f32x4){0.f, 0.f, 0.f, 0.f};

    f16x8 wf[2][8];
    #pragma unroll
    for (int ct = 0; ct < 8; ++ct)
        wf[0][ct] = *(const f16x8*)(wbase + (long)ct * 16 * 256);

    #pragma unroll
    for (int s = 0; s < 8; ++s) {
        const int kb = s * 32 + q16 * 8;
        // issue next k-step's 8 Wg loads first (max lead time over the MFMA burst)
        if (s < 7) {
            #pragma unroll
            for (int ct = 0; ct < 8; ++ct)
                wf[(s + 1) & 1][ct] = *(const f16x8*)(wbase + (long)ct * 16 * 256 + (s + 1) * 32);
        }
        f16x8 bfr[4];
        #pragma unroll
        for (int rt = 0; rt < 4; ++rt) {
            int row = rt * 16 + r16;
            bfr[rt] = *(const f16x8*)&atile[(row * 256 + kb) ^ ((row & 7) << 3)];
        }
        #pragma unroll
        for (int ct = 0; ct < 8; ++ct)
            #pragma unroll
            for (int rt = 0; rt < 4; ++rt)
                acc[ct][rt] = __builtin_amdgcn_mfma_f32_16x16x32_f16(
                    wf[s & 1][ct], bfr[rt], acc[ct][rt], 0, 0, 0);
    }

    // Epilogue: rt-outer so a lane's consecutive stores walk cols (fast line completion).
    if (w < 2) {
        #pragma unroll
        for (int rt = 0; rt < 4; ++rt) {
            const long row = gr0 + rt * 16 + r16;
            const bool ok = row < N_NODES;
            #pragma unroll
            for (int ct = 0; ct < 8; ++ct) {
                const int colb = c0 + ct * 16 + q16 * 4;
                if (ok) {
                    union { ushort4 u; f16_t h[4]; } t;
                    t.h[0] = (f16_t)acc[ct][rt][0]; t.h[1] = (f16_t)acc[ct][rt][1];
                    t.h[2] = (f16_t)acc[ct][rt][2]; t.h[3] = (f16_t)acc[ct][rt][3];
                    *(ushort4*)&Pself[row * 256 + colb] = t.u;
                }
            }
        }
    } else {
        #pragma unroll
        for (int rt = 0; rt < 4; ++rt) {
            const long row = gr0 + rt * 16 + r16;
            const bool ok = row < N_NODES;
            #pragma unroll
            for (int ct = 0; ct < 8; ++ct) {
                const int colb = (c0 - 256) + ct * 16 + q16 * 4;
                unsigned int pk = pk_fp8x4(acc[ct][rt][0], acc[ct][rt][1],
                                           acc[ct][rt][2], acc[ct][rt][3]);
                if (ok) *(unsigned int*)&Pneigh8[row * 256 + colb] = pk;
            }
        }
    }
}

// ---------------- Kernel 2: out[b] = Pself[ni[b]] + mean_s fp8(Pneigh[nb[b,s]]) ----------------
__global__ __launch_bounds__(256) void gather_add(
    const f16_t* __restrict__ Pself, const unsigned char* __restrict__ P8,
    const int* __restrict__ node_idx, const int* __restrict__ neigh_idx,
    float* __restrict__ out)
{
    const int tid = threadIdx.x, lane = tid & 63, w = tid >> 6;
    const long b0 = (long)blockIdx.x * 8 + w * 2;   // rows b0, b0+1
    const int c4 = lane * 4;

    int ns0[NSAMP], ns1[NSAMP];
    #pragma unroll
    for (int s = 0; s < NSAMP; ++s) ns0[s] = neigh_idx[b0 * NSAMP + s];
    #pragma unroll
    for (int s = 0; s < NSAMP; ++s) ns1[s] = neigh_idx[(b0 + 1) * NSAMP + s];
    const int sn0 = node_idx[b0], sn1 = node_idx[b0 + 1];

    const ushort4 sv0 = *(const ushort4*)&Pself[(long)sn0 * 256 + c4];
    const ushort4 sv1 = *(const ushort4*)&Pself[(long)sn1 * 256 + c4];

    // issue all 50 gathered 4B loads before decoding (max MLP)
    unsigned int v0[NSAMP], v1[NSAMP];
    #pragma unroll
    for (int s = 0; s < NSAMP; ++s)
        v0[s] = *(const unsigned int*)&P8[(long)ns0[s] * 256 + c4];
    #pragma unroll
    for (int s = 0; s < NSAMP; ++s)
        v1[s] = *(const unsigned int*)&P8[(long)ns1[s] * 256 + c4];

    float4 a0 = make_float4(0.f, 0.f, 0.f, 0.f);
    float4 a1 = make_float4(0.f, 0.f, 0.f, 0.f);
    #pragma unroll
    for (int s = 0; s < NSAMP; ++s) acc_fp8x4(v0[s], a0);
    #pragma unroll
    for (int s = 0; s < NSAMP; ++s) acc_fp8x4(v1[s], a1);

    const float inv = 1.0f / (float)NSAMP;
    float4 o0, o1;
    o0.x = h2f(sv0.x) + a0.x * inv; o0.y = h2f(sv0.y) + a0.y * inv;
    o0.z = h2f(sv0.z) + a0.z * inv; o0.w = h2f(sv0.w) + a0.w * inv;
    o1.x = h2f(sv1.x) + a1.x * inv; o1.y = h2f(sv1.y) + a1.y * inv;
    o1.z = h2f(sv1.z) + a1.z * inv; o1.w = h2f(sv1.w) + a1.w * inv;
    *(float4*)&out[b0 * OUT_F + c4] = o0;
    *(float4*)&out[(b0 + 1) * OUT_F + c4] = o1;
}

// ---------------- Fallback (monolithic) if ws too small ----------------
__device__ __forceinline__ int swz_bf(int row, int us_idx) {
    return us_idx ^ ((row & 7) << 3);
}
__device__ __forceinline__ void store_bf4(unsigned short* comb, int r, int col, float4 f) {
    union { ushort4 u; bf16_t b[4]; } t;
    t.b[0] = (bf16_t)f.x; t.b[1] = (bf16_t)f.y;
    t.b[2] = (bf16_t)f.z; t.b[3] = (bf16_t)f.w;
    *(ushort4*)&comb[swz_bf(r, r * K2 + col)] = t.u;
}
__global__ __launch_bounds__(256, 4) void sage_fused(
    const float* __restrict__ features, const int* __restrict__ node_idx,
    const int* __restrict__ neigh_idx, const float* __restrict__ W,
    float* __restrict__ out)
{
    __shared__ unsigned short comb[16 * K2];
    const int tid = threadIdx.x, lane = tid & 63, wy = tid >> 6;
    const int b0 = blockIdx.x * 16;
    const int col4 = lane * 4;
    #pragma unroll
    for (int i = 0; i < 4; ++i) {
        const int r = wy * 4 + i;
        const long b = b0 + r;
        int nidx[NSAMP];
        #pragma unroll
        for (int s = 0; s < NSAMP; ++s) nidx[s] = neigh_idx[b * NSAMP + s];
        const int self_n = node_idx[b];
        const float4 sf = *(const float4*)&features[(long)self_n * IN_F + col4];
        float4 v[13];
        #pragma unroll
        for (int s = 0; s < 13; ++s)
            v[s] = *(const float4*)&features[(long)nidx[s] * IN_F + col4];
        float4 acc = v[0];
        #pragma unroll
        for (int s = 1; s < 13; ++s) {
            acc.x += v[s].x; acc.y += v[s].y; acc.z += v[s].z; acc.w += v[s].w;
        }
        #pragma unroll
        for (int s = 13; s < NSAMP; ++s)
            v[s - 13] = *(const float4*)&features[(long)nidx[s] * IN_F + col4];
        #pragma unroll
        for (int s = 0; s < 12; ++s) {
            acc.x += v[s].x; acc.y += v[s].y; acc.z += v[s].z; acc.w += v[s].w;
        }
        const float inv = 1.0f / (float)NSAMP;
        acc.x *= inv; acc.y *= inv; acc.z *= inv; acc.w *= inv;
        store_bf4(comb, r, col4, sf);
        store_bf4(comb, r, IN_F + col4, acc);
    }
    __syncthreads();
    const int c0 = wy * 64, arow = lane & 15, kq = (lane >> 4) * 8;
    f32x4 acc[4];
    #pragma unroll
    for (int t = 0; t < 4; ++t) acc[t] = (f32x4){0.f, 0.f, 0.f, 0.f};
    #pragma unroll
    for (int ks = 0; ks < 16; ++ks) {
        const int kb = ks * 32 + kq;
        const bf16x8 af = *(const bf16x8*)&comb[swz_bf(arow, arow * K2 + kb)];
        #pragma unroll
        for (int t = 0; t < 4; ++t) {
            const float* wp = &W[(long)(c0 + t * 16 + arow) * K2 + kb];
            const float4 w0 = *(const float4*)wp;
            const float4 w1 = *(const float4*)(wp + 4);
            bf16x8 bf;
            bf[0] = (bf16_t)w0.x; bf[1] = (bf16_t)w0.y;
            bf[2] = (bf16_t)w0.z; bf[3] = (bf16_t)w0.w;
            bf[4] = (bf16_t)w1.x; bf[5] = (bf16_t)w1.y;
            bf[6] = (bf16_t)w1.z; bf[7] = (bf16_t)w1.w;
            acc[t] = __builtin_amdgcn_mfma_f32_16x16x32_bf16(af, bf, acc[t], 0, 0, 0);
        }
    }
    #pragma unroll
    for (int t = 0; t < 4; ++t) {
        const int col = c0 + t * 16 + arow;
        #pragma unroll
        for (int j = 0; j < 4; ++j) {
            const int row = b0 + (lane >> 4) * 4 + j;
            out[(long)row * OUT_F + col] = acc[t][j];
        }
    }
}

extern "C" void kernel_launch(void* const* d_in, const int* in_sizes, int n_in,
                              void* d_out, int out_size, void* d_ws, size_t ws_size,
                              hipStream_t stream) {
    const float* features  = (const float*)d_in[0];
    const int*   node_idx  = (const int*)d_in[1];
    const int*   neigh_idx = (const int*)d_in[2];
    const float* W         = (const float*)d_in[3];
    float*       out       = (float*)d_out;

    if (ws_size >= (size_t)WS_NEED) {
        f16_t*         Pself  = (f16_t*)d_ws;
        unsigned char* P8     = (unsigned char*)d_ws + P8_OFF;
        f16_t*         Wg     = (f16_t*)((char*)d_ws + WG_OFF);
        wconv<<<512, 256, 0, stream>>>(W, Wg);
        proj_gemm<<<1563, 256, 0, stream>>>(features, Wg, Pself, P8);
        gather_add<<<BATCH / 8, 256, 0, stream>>>(Pself, P8, node_idx, neigh_idx, out);
    } else {
        sage_fused<<<BATCH / 16, 256, 0, stream>>>(features, node_idx, neigh_idx, W, out);
    }
}